// Round 1
// baseline (21.134 us; speedup 1.0000x reference)
//
#include <hip/hip_runtime.h>

// EvenLayer (neural BP even/check layer), MI355X.
//
// Structure exploited: mask = kron(eye(256), ones(16,16)-eye(16)) makes both
// "matmuls" block-diagonal with 16x16 blocks. Per (batch b, check c):
//   la[j]  = log(|x[b,c*16+j]| + eps)
//   bit[j] = x[b,c*16+j] < 0
//   out[b,c*16+i] = logratio( bipolar_i * exp( sum_{j!=i} la[j]*W[c*16+j, c*16+i] ) )
//   bipolar_i = 1-2*(parity of bits j!=i)
// Only the 256 diagonal 16x16 blocks of even_weights are read; mask never read.

constexpr int M_CHECKS = 256;
constexpr int DC = 16;
constexpr int NEURONS = M_CHECKS * DC;   // 4096
constexpr int BATCH = 1024;
constexpr float EPS = 1e-8f;

// grid: 4096 blocks = 256 checks x 16 batch-chunks (64 batches each)
// block: 256 threads = 16 local batches x 16 edges; 4 passes over the chunk
__global__ __launch_bounds__(256) void even_layer_kernel(
    const float* __restrict__ x,      // [BATCH, NEURONS]
    const float* __restrict__ w,      // [NEURONS, NEURONS], only block-diag used
    float* __restrict__ out)          // [BATCH, NEURONS]
{
    __shared__ float Wsh[DC][DC];     // Wsh[j][i] = masked weight (diag zeroed)

    const int c     = blockIdx.x & (M_CHECKS - 1);  // consecutive blocks -> consecutive c
    const int chunk = blockIdx.x >> 8;              // 0..15, 64 batches each
    const int tid   = (int)threadIdx.x;
    const int bi    = tid >> 4;                     // local batch sub-index 0..15
    const int i     = tid & 15;                     // edge within check

    // Stage the 16x16 weight block; applying the mask == zeroing the diagonal.
    {
        const int j = bi;
        float wv = w[(size_t)(c * DC + j) * NEURONS + (size_t)(c * DC + i)];
        Wsh[j][i] = (j == i) ? 0.0f : wv;
    }
    __syncthreads();

    const int lane  = tid & 63;
    const int gbase = lane & 48;      // base lane of this 16-lane group in the wave

    #pragma unroll
    for (int p = 0; p < 4; ++p) {
        const int b = chunk * 64 + p * 16 + bi;
        const size_t idx = (size_t)b * NEURONS + (size_t)(c * DC + i);

        const float xv = x[idx];
        const float la = logf(fabsf(xv) + EPS);
        const int bit = (xv < 0.0f) ? 1 : 0;

        // parity of sign bits over the 16-lane group, excluding self
        const unsigned long long m = __ballot(bit);
        int par = __popcll((m >> gbase) & 0xFFFFull) & 1;
        par ^= bit;

        // dot = sum_j la[j] * Wsh[j][i]   (diagonal already zeroed)
        float dot = 0.0f;
        #pragma unroll
        for (int jj = 0; jj < DC; ++jj) {
            const float lav = __shfl(la, gbase + jj, 64);
            dot = fmaf(lav, Wsh[jj][i], dot);
        }

        const float e = expf(dot);
        const float even = par ? -e : e;
        const float r = logf((1.0f + even + EPS) / (1.0f - even + EPS));
        out[idx] = r;
    }
}

extern "C" void kernel_launch(void* const* d_in, const int* in_sizes, int n_in,
                              void* d_out, int out_size, void* d_ws, size_t ws_size,
                              hipStream_t stream) {
    const float* x = (const float*)d_in[0];          // [1024, 4096]
    const float* w = (const float*)d_in[1];          // [4096, 4096] even_weights
    // d_in[2] = w_even2odd_mask: structure hard-coded, never read
    float* out = (float*)d_out;                      // [1024, 4096] f32

    dim3 grid(M_CHECKS * (BATCH / 64));              // 4096
    dim3 block(256);
    hipLaunchKernelGGL(even_layer_kernel, grid, block, 0, stream, x, w, out);
}

// Round 2
// 17.805 us; speedup vs baseline: 1.1869x; 1.1869x over previous
//
#include <hip/hip_runtime.h>

// EvenLayer (neural BP even/check layer), MI355X — R2.
//
// mask = kron(eye(256), ones(16,16)-eye(16)) => both matmuls are block-diagonal
// with 16x16 blocks. One THREAD per (batch b, check c):
//   - loads its own 16 x values (4x float4, 16B/lane coalesced)
//   - la[j] = logf(|x_j|+eps), sign bits + parity via popcount (no cross-lane ops)
//   - 16x16 mat-vec from LDS-staged weight block (diag zeroed = mask applied),
//     float4 ds_read_b128, padded stride => conflict-free
//   - epilogue exp + log-ratio, 4x float4 stores
// Same op order as the R1 bit-exact kernel (fmaf chain j=0..15, zeroed diag,
// logf((1+m+eps)/(1-m+eps))) => expect absmax 0 again.

constexpr int M_CHECKS = 256;
constexpr int DC = 16;
constexpr int NEURONS = M_CHECKS * DC;   // 4096
constexpr int BATCH = 1024;
constexpr float EPS = 1e-8f;

constexpr int CB = 16;    // checks per block
constexpr int BB = 16;    // batches per block
constexpr int BS4 = 65;   // float4 stride per check in LDS (65*4=260 words; 260%32=4 => 2-way, free)

__global__ __launch_bounds__(256) void even_layer_kernel(
    const float* __restrict__ x,      // [BATCH, NEURONS]
    const float* __restrict__ w,      // [NEURONS, NEURONS], only block-diag used
    float* __restrict__ out)          // [BATCH, NEURONS]
{
    __shared__ float4 Wsh[CB * BS4];  // 16.6 KB

    const int tid = (int)threadIdx.x;
    const int cb  = (int)blockIdx.x & 15;   // check-block 0..15
    const int bb  = (int)blockIdx.x >> 4;   // batch-block 0..63

    // ---- stage 16 weight blocks (16 KB), diag zeroed (== mask applied) ----
    {
        const int cl = tid >> 4;            // local check 0..15
        const int j  = tid & 15;            // row within block
        const int c  = cb * CB + cl;
        const float* src = w + (size_t)(c * DC + j) * NEURONS + (size_t)(c * DC);
        #pragma unroll
        for (int k = 0; k < 4; ++k) {
            float4 v = *(const float4*)(src + 4 * k);
            if ((j >> 2) == k) {            // zero the diagonal element (col i == j)
                if ((j & 3) == 0) v.x = 0.0f;
                else if ((j & 3) == 1) v.y = 0.0f;
                else if ((j & 3) == 2) v.z = 0.0f;
                else v.w = 0.0f;
            }
            Wsh[cl * BS4 + j * 4 + k] = v;
        }
    }
    __syncthreads();

    // ---- one thread per (b, c) ----
    const int bi = tid >> 4;                // local batch 0..15
    const int ci = tid & 15;                // local check 0..15 (fast => coalesced)
    const int b  = bb * BB + bi;
    const int c  = cb * CB + ci;

    const float* xp = x + (size_t)b * NEURONS + (size_t)(c * DC);

    float la[DC];
    int sbits = 0;

    #define LOADPROC(XV, J)                                   \
        { const float xv_ = (XV);                             \
          la[J] = logf(fabsf(xv_) + EPS);                     \
          if (xv_ < 0.0f) sbits |= (1 << (J)); }

    #pragma unroll
    for (int k = 0; k < 4; ++k) {
        const float4 v = *(const float4*)(xp + 4 * k);
        LOADPROC(v.x, 4 * k + 0)
        LOADPROC(v.y, 4 * k + 1)
        LOADPROC(v.z, 4 * k + 2)
        LOADPROC(v.w, 4 * k + 3)
    }
    const int sall = __popc(sbits) & 1;     // parity of all 16 sign bits

    // ---- acc[i] = sum_j la[j] * W[j][i] (diag term adds exact 0) ----
    float acc[DC];
    #pragma unroll
    for (int i = 0; i < DC; ++i) acc[i] = 0.0f;

    const int wbase = ci * BS4;
    #pragma unroll
    for (int j = 0; j < DC; ++j) {
        const float lj = la[j];
        const float4 w0 = Wsh[wbase + j * 4 + 0];
        const float4 w1 = Wsh[wbase + j * 4 + 1];
        const float4 w2 = Wsh[wbase + j * 4 + 2];
        const float4 w3 = Wsh[wbase + j * 4 + 3];
        acc[0]  = fmaf(lj, w0.x, acc[0]);
        acc[1]  = fmaf(lj, w0.y, acc[1]);
        acc[2]  = fmaf(lj, w0.z, acc[2]);
        acc[3]  = fmaf(lj, w0.w, acc[3]);
        acc[4]  = fmaf(lj, w1.x, acc[4]);
        acc[5]  = fmaf(lj, w1.y, acc[5]);
        acc[6]  = fmaf(lj, w1.z, acc[6]);
        acc[7]  = fmaf(lj, w1.w, acc[7]);
        acc[8]  = fmaf(lj, w2.x, acc[8]);
        acc[9]  = fmaf(lj, w2.y, acc[9]);
        acc[10] = fmaf(lj, w2.z, acc[10]);
        acc[11] = fmaf(lj, w2.w, acc[11]);
        acc[12] = fmaf(lj, w3.x, acc[12]);
        acc[13] = fmaf(lj, w3.y, acc[13]);
        acc[14] = fmaf(lj, w3.z, acc[14]);
        acc[15] = fmaf(lj, w3.w, acc[15]);
    }

    // ---- epilogue: exp, sign, log-ratio; float4 stores ----
    float* op = out + (size_t)b * NEURONS + (size_t)(c * DC);

    #define EPI(RCOMP, I)                                                   \
        { const float e_ = expf(acc[I]);                                    \
          const int par_ = sall ^ ((sbits >> (I)) & 1);                     \
          const float even_ = par_ ? -e_ : e_;                              \
          RCOMP = logf((1.0f + even_ + EPS) / (1.0f - even_ + EPS)); }

    #pragma unroll
    for (int k = 0; k < 4; ++k) {
        float4 r;
        EPI(r.x, 4 * k + 0)
        EPI(r.y, 4 * k + 1)
        EPI(r.z, 4 * k + 2)
        EPI(r.w, 4 * k + 3)
        *(float4*)(op + 4 * k) = r;
    }

    #undef LOADPROC
    #undef EPI
}

extern "C" void kernel_launch(void* const* d_in, const int* in_sizes, int n_in,
                              void* d_out, int out_size, void* d_ws, size_t ws_size,
                              hipStream_t stream) {
    const float* x = (const float*)d_in[0];          // [1024, 4096]
    const float* w = (const float*)d_in[1];          // [4096, 4096] even_weights
    // d_in[2] = w_even2odd_mask: structure hard-coded, never read
    float* out = (float*)d_out;                      // [1024, 4096] f32

    dim3 grid((BATCH / BB) * (M_CHECKS / CB));       // 64 * 16 = 1024 blocks
    dim3 block(256);
    hipLaunchKernelGGL(even_layer_kernel, grid, block, 0, stream, x, w, out);
}